// Round 3
// baseline (139.814 us; speedup 1.0000x reference)
//
#include <hip/hip_runtime.h>
#include <math.h>

#define N_FZ    60
#define N_KEZ   20
#define N_TINT  30
#define N_ALPHA 200
#define NORB    2000
#define NTIMES  1000
#define BLOCK   256
#define G_LD    201   // slab row stride in floats (col 200 = +1 neighbor)

// ---------------------------------------------------------------------------
// Pass 1: fused transpose + precompute.
// xd[t][orb] = (a_ind unclipped, dMag or +inf if geom-masked).
// ---------------------------------------------------------------------------
__global__ __launch_bounds__(256) void prep_kernel(
    const float* __restrict__ alpha,      // (NORB, NTIMES)
    const float* __restrict__ dMag,       // (NORB, NTIMES)
    const float* __restrict__ alphas,     // (N_ALPHA,)
    const float* __restrict__ log_alphas, // (N_ALPHA,)
    float2* __restrict__ xd)              // (NTIMES, NORB)
{
    __shared__ float2 tile[32][33];

    const float la0    = log_alphas[0];
    const float inv_la = 1.0f / (log_alphas[1] - la0);
    const float alo    = alphas[0];
    const float ahi    = alphas[N_ALPHA - 1];

    const int t0 = blockIdx.x * 32;
    const int o0 = blockIdx.y * 32;
    const int tx = threadIdx.x, ty = threadIdx.y;

    #pragma unroll
    for (int r = 0; r < 4; ++r) {
        int orb = o0 + ty + 8 * r;
        int t   = t0 + tx;
        float2 v = make_float2(0.0f, __builtin_inff());
        if (orb < NORB && t < NTIMES) {
            float a  = alpha[(size_t)orb * NTIMES + t];
            float dm = dMag [(size_t)orb * NTIMES + t];
            bool geom = (a >= alo) && (a <= ahi);
            float x = (log10f(a) - la0) * inv_la;
            v = make_float2(x, geom ? dm : __builtin_inff());
        }
        tile[ty + 8 * r][tx] = v;
    }
    __syncthreads();
    #pragma unroll
    for (int r = 0; r < 4; ++r) {
        int tt  = ty + 8 * r;
        int t   = t0 + tt;
        int orb = o0 + tx;
        if (orb < NORB && t < NTIMES)
            xd[(size_t)t * NORB + orb] = tile[tx][tt];
    }
}

// ---------------------------------------------------------------------------
// Pass 2: block = one t.  Lane = s*32+k (s: orbit slot, k: tint).
// Slab g[30][201] in LDS (24.1 KB -> 6 blocks/CU); row stride 201 words
// makes the 30 k-lane reads conflict-free ((9k+a) mod 32, gcd(9,32)=1).
// Per wave-iteration: 2 orbits x 30 tints = 60 evals, 2 ds_read_b32.
// ---------------------------------------------------------------------------
__global__ __launch_bounds__(BLOCK) void pdet3_kernel(
    const float2* __restrict__ xd,        // (NTIMES, NORB)
    const float* __restrict__ fZ_vals,    // (NTIMES,)
    const float* __restrict__ kEZ_val,    // scalar
    const float* __restrict__ grid,       // (N_FZ, N_KEZ, N_TINT, N_ALPHA)
    const float* __restrict__ kEZs,       // (N_KEZ,)
    const float* __restrict__ log_fZs,    // (N_FZ,)
    float* __restrict__ out)              // (NTIMES, N_TINT)
{
    __shared__ float g[N_TINT * G_LD];    // 24120 B
    __shared__ int   wsum[4][N_TINT];

    const int t   = blockIdx.x;
    const int tid = threadIdx.x;

    // fZ0 (double to match np at floor boundaries)
    const float lf0    = log_fZs[0];
    const float lfstep = log_fZs[1] - lf0;
    double fZ_ind = (log10((double)fZ_vals[t]) - (double)lf0) * (1.0 / (double)lfstep);
    int fZ0 = (int)floor(fZ_ind) + 1;
    fZ0 = min(max(fZ0, 0), N_FZ - 2);

    // searchsorted(kEZs, kEZ_val, 'right') - 1
    const float kv = kEZ_val[0];
    int kidx = -1;
    #pragma unroll
    for (int i = 0; i < N_KEZ; ++i) kidx += (kEZs[i] <= kv) ? 1 : 0;
    if (kidx < 0) kidx += N_KEZ;

    // ---- stage slab rows (200 floats + 1 neighbor) into LDS ----
    const float* src = grid + ((size_t)fZ0 * N_KEZ + kidx) * (N_TINT * N_ALPHA);
    // tasks: 30 rows x 51 chunks (50 float4 + 1 tail scalar)
    for (int m = tid; m < N_TINT * 51; m += BLOCK) {
        int k = m / 51;
        int c = m - 51 * k;
        if (c < 50) {
            float4 v = *(const float4*)(src + (size_t)k * N_ALPHA + 4 * c);
            int b = k * G_LD + 4 * c;
            g[b + 0] = v.x; g[b + 1] = v.y; g[b + 2] = v.z; g[b + 3] = v.w;
        } else {
            // col 200 = first element of next row (in-bounds within grid)
            g[k * G_LD + 200] = src[(size_t)k * N_ALPHA + 200];
        }
    }
    __syncthreads();

    const int lane = tid & 63;
    const int w    = tid >> 6;
    const int s    = lane >> 5;                 // orbit slot within wave
    const int k    = lane & 31;                 // tint (30 used)
    const int krow = min(k, N_TINT - 1) * G_LD; // clamp idle lanes to row 29
    const bool kvalid = (k < N_TINT);

    const float2* row = xd + (size_t)t * NORB;
    int cnt = 0;
    #pragma unroll 4
    for (int i = 0; i < NORB / 8; ++i) {        // 250 iterations
        int p = w + 4 * i;                      // orbit-pair index 0..999
        float2 v = row[2 * p + s];              // half-wave-uniform -> broadcast
        float x  = v.x;
        float dm = v.y;
        // clamp in float; geom-masked orbits have dm=+inf so result unaffected
        float xc = fminf(fmaxf(x, 0.0f), (float)(N_ALPHA - 1));
        int   a0 = (int)xc;                     // trunc
        float dal = xc - (float)a0;
        int   a0s = min(a0, N_ALPHA - 2);
        float g0 = g[krow + a0s];
        float g1 = g[krow + a0s + 1];
        float dim = fmaf(dal, g1 - g0, g0);
        cnt += (dm < dim) ? 1 : 0;
    }

    // combine the two orbit slots: lane k <- lane k + lane k+32
    cnt += __shfl_xor(cnt, 32, 64);
    if (kvalid && s == 0) wsum[w][k] = cnt;
    __syncthreads();

    if (tid < N_TINT) {
        int tot = wsum[0][tid] + wsum[1][tid] + wsum[2][tid] + wsum[3][tid];
        out[(size_t)t * N_TINT + tid] = (float)tot / (float)NORB;
    }
}

// ---------------------------------------------------------------------------
// Fallback (no workspace): round-1 kernel, correct but slower.
// ---------------------------------------------------------------------------
__global__ __launch_bounds__(BLOCK) void pdet_kernel(
    const float* __restrict__ alpha, const float* __restrict__ dMag,
    const float* __restrict__ fZ_vals, const float* __restrict__ kEZ_val,
    const float* __restrict__ grid, const float* __restrict__ kEZs,
    const float* __restrict__ alphas, const float* __restrict__ log_fZs,
    const float* __restrict__ log_alphas, float* __restrict__ out)
{
    __shared__ float2 pairs[N_TINT * N_ALPHA];
    __shared__ int    wsum[BLOCK / 64][N_TINT];

    const int t   = blockIdx.x;
    const int tid = threadIdx.x;

    const float la0    = log_alphas[0];
    const float inv_la = 1.0f / (log_alphas[1] - la0);
    const float alo    = alphas[0];
    const float ahi    = alphas[N_ALPHA - 1];

    const float lf0    = log_fZs[0];
    const float lfstep = log_fZs[1] - lf0;
    double fZ_ind = (log10((double)fZ_vals[t]) - (double)lf0) * (1.0 / (double)lfstep);
    int fZ0 = (int)floor(fZ_ind) + 1;
    fZ0 = min(max(fZ0, 0), N_FZ - 2);

    const float kv = kEZ_val[0];
    int kidx = -1;
    #pragma unroll
    for (int i = 0; i < N_KEZ; ++i) kidx += (kEZs[i] <= kv) ? 1 : 0;
    if (kidx < 0) kidx += N_KEZ;

    const float* src = grid + ((size_t)fZ0 * N_KEZ + kidx) * (N_TINT * N_ALPHA);
    const float4* src4 = (const float4*)src;
    for (int j = tid; j < (N_TINT * N_ALPHA) / 4; j += BLOCK) {
        float4 v  = src4[j];
        float nxt = src[4 * j + 4];
        pairs[4 * j + 0] = make_float2(v.x, v.y);
        pairs[4 * j + 1] = make_float2(v.y, v.z);
        pairs[4 * j + 2] = make_float2(v.z, v.w);
        pairs[4 * j + 3] = make_float2(v.w, nxt);
    }
    __syncthreads();

    int cnt[N_TINT];
    #pragma unroll
    for (int k = 0; k < N_TINT; ++k) cnt[k] = 0;

    for (int orb = tid; orb < NORB; orb += BLOCK) {
        float a  = alpha[(size_t)orb * NTIMES + t];
        float dm = dMag [(size_t)orb * NTIMES + t];
        bool geom = (a >= alo) && (a <= ahi);
        float a_ind = (log10f(a) - la0) * inv_la;
        int a0 = (int)a_ind;
        a0 = min(max(a0, 0), N_ALPHA - 1);
        float dal = a_ind - (float)a0;
        int a0s = min(a0, N_ALPHA - 2);
        if (!geom) dm = __builtin_inff();

        #pragma unroll
        for (int k = 0; k < N_TINT; ++k) {
            float2 p = pairs[k * N_ALPHA + a0s];
            float dim = p.x + dal * (p.y - p.x);
            cnt[k] += (dm < dim) ? 1 : 0;
        }
    }

    const int lane = tid & 63;
    const int wid  = tid >> 6;
    #pragma unroll
    for (int k = 0; k < N_TINT; ++k) {
        int c = cnt[k];
        c += __shfl_xor(c, 32, 64);
        c += __shfl_xor(c, 16, 64);
        c += __shfl_xor(c,  8, 64);
        c += __shfl_xor(c,  4, 64);
        c += __shfl_xor(c,  2, 64);
        c += __shfl_xor(c,  1, 64);
        if (lane == 0) wsum[wid][k] = c;
    }
    __syncthreads();

    if (tid < N_TINT) {
        int tot = wsum[0][tid] + wsum[1][tid] + wsum[2][tid] + wsum[3][tid];
        out[(size_t)t * N_TINT + tid] = (float)tot / (float)NORB;
    }
}

extern "C" void kernel_launch(void* const* d_in, const int* in_sizes, int n_in,
                              void* d_out, int out_size, void* d_ws, size_t ws_size,
                              hipStream_t stream) {
    const float* alpha      = (const float*)d_in[0];
    const float* dMag       = (const float*)d_in[1];
    const float* fZ_vals    = (const float*)d_in[2];
    const float* kEZ_val    = (const float*)d_in[3];
    const float* grid       = (const float*)d_in[4];
    const float* kEZs       = (const float*)d_in[5];
    const float* alphas     = (const float*)d_in[6];
    const float* log_fZs    = (const float*)d_in[7];
    const float* log_alphas = (const float*)d_in[8];
    float* out = (float*)d_out;

    const size_t need = (size_t)NTIMES * NORB * sizeof(float2);
    if (ws_size >= need) {
        dim3 gb((NTIMES + 31) / 32, (NORB + 31) / 32);
        dim3 tb(32, 8);
        prep_kernel<<<gb, tb, 0, stream>>>(alpha, dMag, alphas, log_alphas,
                                           (float2*)d_ws);
        pdet3_kernel<<<NTIMES, BLOCK, 0, stream>>>(
            (const float2*)d_ws, fZ_vals, kEZ_val, grid, kEZs, log_fZs, out);
    } else {
        pdet_kernel<<<NTIMES, BLOCK, 0, stream>>>(
            alpha, dMag, fZ_vals, kEZ_val, grid, kEZs, alphas, log_fZs,
            log_alphas, out);
    }
}

// Round 4
// 136.818 us; speedup vs baseline: 1.0219x; 1.0219x over previous
//
#include <hip/hip_runtime.h>
#include <math.h>

#define N_FZ    60
#define N_KEZ   20
#define N_TINT  30
#define N_ALPHA 200
#define NORB    2000
#define NTIMES  1000
#define BLOCK   1024
#define G_LD    201   // slab row stride in floats (col 200 = +1 neighbor)

// ---------------------------------------------------------------------------
// Pass 1: fused transpose + full index precompute.
// xd[t][orb] = (xc, dm) where xc = clamp(a_ind, 0, 198.9999) encodes
// a0 = trunc(xc) and dal = fract(xc); dm = +inf when geom-masked.
// ---------------------------------------------------------------------------
__global__ __launch_bounds__(256) void prep_kernel(
    const float* __restrict__ alpha,      // (NORB, NTIMES)
    const float* __restrict__ dMag,       // (NORB, NTIMES)
    const float* __restrict__ alphas,     // (N_ALPHA,)
    const float* __restrict__ log_alphas, // (N_ALPHA,)
    float2* __restrict__ xd)              // (NTIMES, NORB)
{
    __shared__ float2 tile[32][33];

    const float la0    = log_alphas[0];
    const float inv_la = 1.0f / (log_alphas[1] - la0);
    const float alo    = alphas[0];
    const float ahi    = alphas[N_ALPHA - 1];

    const int t0 = blockIdx.x * 32;
    const int o0 = blockIdx.y * 32;
    const int tx = threadIdx.x, ty = threadIdx.y;

    #pragma unroll
    for (int r = 0; r < 4; ++r) {
        int orb = o0 + ty + 8 * r;
        int t   = t0 + tx;
        float2 v = make_float2(0.0f, __builtin_inff());
        if (orb < NORB && t < NTIMES) {
            float a  = alpha[(size_t)orb * NTIMES + t];
            float dm = dMag [(size_t)orb * NTIMES + t];
            bool geom = (a >= alo) && (a <= ahi);
            float x = (log10f(a) - la0) * inv_la;
            float xc = fminf(fmaxf(x, 0.0f), 198.9999f);
            v = make_float2(xc, geom ? dm : __builtin_inff());
        }
        tile[ty + 8 * r][tx] = v;
    }
    __syncthreads();
    #pragma unroll
    for (int r = 0; r < 4; ++r) {
        int tt  = ty + 8 * r;
        int t   = t0 + tt;
        int orb = o0 + tx;
        if (orb < NORB && t < NTIMES)
            xd[(size_t)t * NORB + orb] = tile[tx][tt];
    }
}

// ---------------------------------------------------------------------------
// Pass 2: block = one t, 1024 threads (16 waves) -> 2 blocks/CU = 32 waves/CU.
// Lane = s*32+k (s: orbit slot, k: tint).  Slab g[30][201] in LDS; stride 201
// words keeps the 30 k-lane reads conflict-free.  Hot loop decode is 3 VALU
// (cvt_u32 trunc, v_fract, lshl_add) + one ds_read2_b32 + 4 compute ops.
// ---------------------------------------------------------------------------
__global__ __launch_bounds__(BLOCK) void pdet4_kernel(
    const float2* __restrict__ xd,        // (NTIMES, NORB)
    const float* __restrict__ fZ_vals,    // (NTIMES,)
    const float* __restrict__ kEZ_val,    // scalar
    const float* __restrict__ grid,       // (N_FZ, N_KEZ, N_TINT, N_ALPHA)
    const float* __restrict__ kEZs,       // (N_KEZ,)
    const float* __restrict__ log_fZs,    // (N_FZ,)
    float* __restrict__ out)              // (NTIMES, N_TINT)
{
    __shared__ float g[N_TINT * G_LD];    // 24120 B
    __shared__ int   wsum[16][N_TINT];

    const int t   = blockIdx.x;
    const int tid = threadIdx.x;

    // fZ0 (double to match np at floor boundaries)
    const float lf0    = log_fZs[0];
    const float lfstep = log_fZs[1] - lf0;
    double fZ_ind = (log10((double)fZ_vals[t]) - (double)lf0) * (1.0 / (double)lfstep);
    int fZ0 = (int)floor(fZ_ind) + 1;
    fZ0 = min(max(fZ0, 0), N_FZ - 2);

    // searchsorted(kEZs, kEZ_val, 'right') - 1
    const float kv = kEZ_val[0];
    int kidx = -1;
    #pragma unroll
    for (int i = 0; i < N_KEZ; ++i) kidx += (kEZs[i] <= kv) ? 1 : 0;
    if (kidx < 0) kidx += N_KEZ;

    // ---- stage slab rows (200 floats + 1 neighbor) into LDS ----
    const float* src = grid + ((size_t)fZ0 * N_KEZ + kidx) * (N_TINT * N_ALPHA);
    for (int m = tid; m < N_TINT * 51; m += BLOCK) {
        int k = m / 51;
        int c = m - 51 * k;
        if (c < 50) {
            float4 v = *(const float4*)(src + (size_t)k * N_ALPHA + 4 * c);
            int b = k * G_LD + 4 * c;
            g[b + 0] = v.x; g[b + 1] = v.y; g[b + 2] = v.z; g[b + 3] = v.w;
        } else {
            g[k * G_LD + 200] = src[(size_t)k * N_ALPHA + 200];  // +1 neighbor
        }
    }
    __syncthreads();

    const int lane = tid & 63;
    const int w    = tid >> 6;                  // wave 0..15
    const int s    = lane >> 5;                 // orbit slot within wave
    const int k    = lane & 31;                 // tint (30 used)
    const int krow = min(k, N_TINT - 1) * G_LD; // idle lanes alias row 29 (broadcast)

    const float2* row = xd + (size_t)t * NORB;
    int cnt = 0;
    #pragma unroll 3
    for (int i = 0; i < 63; ++i) {              // pairs p = w + 16*i (< 1000)
        int p = w + 16 * i;
        if (p < NORB / 2) {                     // wave-uniform guard
            float2 v = row[2 * p + s];          // half-wave-uniform -> broadcast
            float xc = v.x;
            float dm = v.y;
            unsigned a0 = (unsigned)xc;         // v_cvt_u32_f32 truncates
            float dal = __builtin_amdgcn_fractf(xc);
            const float* gp = &g[krow + a0];
            float g0 = gp[0];
            float g1 = gp[1];                   // merged -> ds_read2_b32
            float dim = fmaf(dal, g1 - g0, g0);
            cnt += (dm < dim) ? 1 : 0;
        }
    }

    // combine the two orbit slots, then cross-wave via LDS
    cnt += __shfl_xor(cnt, 32, 64);
    if (s == 0 && k < N_TINT) wsum[w][k] = cnt;
    __syncthreads();

    if (tid < N_TINT) {
        int tot = 0;
        #pragma unroll
        for (int w2 = 0; w2 < 16; ++w2) tot += wsum[w2][tid];
        out[(size_t)t * N_TINT + tid] = (float)tot * (1.0f / NORB);
    }
}

// ---------------------------------------------------------------------------
// Fallback (no workspace): round-1 kernel, correct but slower.
// ---------------------------------------------------------------------------
__global__ __launch_bounds__(256) void pdet_kernel(
    const float* __restrict__ alpha, const float* __restrict__ dMag,
    const float* __restrict__ fZ_vals, const float* __restrict__ kEZ_val,
    const float* __restrict__ grid, const float* __restrict__ kEZs,
    const float* __restrict__ alphas, const float* __restrict__ log_fZs,
    const float* __restrict__ log_alphas, float* __restrict__ out)
{
    __shared__ float2 pairs[N_TINT * N_ALPHA];
    __shared__ int    wsum[4][N_TINT];

    const int t   = blockIdx.x;
    const int tid = threadIdx.x;

    const float la0    = log_alphas[0];
    const float inv_la = 1.0f / (log_alphas[1] - la0);
    const float alo    = alphas[0];
    const float ahi    = alphas[N_ALPHA - 1];

    const float lf0    = log_fZs[0];
    const float lfstep = log_fZs[1] - lf0;
    double fZ_ind = (log10((double)fZ_vals[t]) - (double)lf0) * (1.0 / (double)lfstep);
    int fZ0 = (int)floor(fZ_ind) + 1;
    fZ0 = min(max(fZ0, 0), N_FZ - 2);

    const float kv = kEZ_val[0];
    int kidx = -1;
    #pragma unroll
    for (int i = 0; i < N_KEZ; ++i) kidx += (kEZs[i] <= kv) ? 1 : 0;
    if (kidx < 0) kidx += N_KEZ;

    const float* src = grid + ((size_t)fZ0 * N_KEZ + kidx) * (N_TINT * N_ALPHA);
    const float4* src4 = (const float4*)src;
    for (int j = tid; j < (N_TINT * N_ALPHA) / 4; j += 256) {
        float4 v  = src4[j];
        float nxt = src[4 * j + 4];
        pairs[4 * j + 0] = make_float2(v.x, v.y);
        pairs[4 * j + 1] = make_float2(v.y, v.z);
        pairs[4 * j + 2] = make_float2(v.z, v.w);
        pairs[4 * j + 3] = make_float2(v.w, nxt);
    }
    __syncthreads();

    int cnt[N_TINT];
    #pragma unroll
    for (int k = 0; k < N_TINT; ++k) cnt[k] = 0;

    for (int orb = tid; orb < NORB; orb += 256) {
        float a  = alpha[(size_t)orb * NTIMES + t];
        float dm = dMag [(size_t)orb * NTIMES + t];
        bool geom = (a >= alo) && (a <= ahi);
        float a_ind = (log10f(a) - la0) * inv_la;
        int a0 = (int)a_ind;
        a0 = min(max(a0, 0), N_ALPHA - 1);
        float dal = a_ind - (float)a0;
        int a0s = min(a0, N_ALPHA - 2);
        if (!geom) dm = __builtin_inff();

        #pragma unroll
        for (int k = 0; k < N_TINT; ++k) {
            float2 p = pairs[k * N_ALPHA + a0s];
            float dim = p.x + dal * (p.y - p.x);
            cnt[k] += (dm < dim) ? 1 : 0;
        }
    }

    const int lane = tid & 63;
    const int wid  = tid >> 6;
    #pragma unroll
    for (int k = 0; k < N_TINT; ++k) {
        int c = cnt[k];
        c += __shfl_xor(c, 32, 64);
        c += __shfl_xor(c, 16, 64);
        c += __shfl_xor(c,  8, 64);
        c += __shfl_xor(c,  4, 64);
        c += __shfl_xor(c,  2, 64);
        c += __shfl_xor(c,  1, 64);
        if (lane == 0) wsum[wid][k] = c;
    }
    __syncthreads();

    if (tid < N_TINT) {
        int tot = wsum[0][tid] + wsum[1][tid] + wsum[2][tid] + wsum[3][tid];
        out[(size_t)t * N_TINT + tid] = (float)tot / (float)NORB;
    }
}

extern "C" void kernel_launch(void* const* d_in, const int* in_sizes, int n_in,
                              void* d_out, int out_size, void* d_ws, size_t ws_size,
                              hipStream_t stream) {
    const float* alpha      = (const float*)d_in[0];
    const float* dMag       = (const float*)d_in[1];
    const float* fZ_vals    = (const float*)d_in[2];
    const float* kEZ_val    = (const float*)d_in[3];
    const float* grid       = (const float*)d_in[4];
    const float* kEZs       = (const float*)d_in[5];
    const float* alphas     = (const float*)d_in[6];
    const float* log_fZs    = (const float*)d_in[7];
    const float* log_alphas = (const float*)d_in[8];
    float* out = (float*)d_out;

    const size_t need = (size_t)NTIMES * NORB * sizeof(float2);
    if (ws_size >= need) {
        dim3 gb((NTIMES + 31) / 32, (NORB + 31) / 32);
        dim3 tb(32, 8);
        prep_kernel<<<gb, tb, 0, stream>>>(alpha, dMag, alphas, log_alphas,
                                           (float2*)d_ws);
        pdet4_kernel<<<NTIMES, BLOCK, 0, stream>>>(
            (const float2*)d_ws, fZ_vals, kEZ_val, grid, kEZs, log_fZs, out);
    } else {
        pdet_kernel<<<NTIMES, 256, 0, stream>>>(
            alpha, dMag, fZ_vals, kEZ_val, grid, kEZs, alphas, log_fZs,
            log_alphas, out);
    }
}

// Round 5
// 128.914 us; speedup vs baseline: 1.0845x; 1.0613x over previous
//
#include <hip/hip_runtime.h>
#include <math.h>

#define N_FZ    60
#define N_KEZ   20
#define N_TINT  30
#define N_ALPHA 200
#define NORB    2000
#define NTIMES  1000
#define BLOCK   1024
#define P_LD    201   // slab row stride in float2 PAIRS (402 words; 18k%32 bank rot)

// ---------------------------------------------------------------------------
// Pass 1: fused transpose + index precompute.
// xd[t][orb] = (xc, dm): xc = clamp(a_ind,0,198.9999) (a0=trunc, dal=fract);
// dm = +inf when geom-masked.
// ---------------------------------------------------------------------------
__global__ __launch_bounds__(256) void prep_kernel(
    const float* __restrict__ alpha,      // (NORB, NTIMES)
    const float* __restrict__ dMag,       // (NORB, NTIMES)
    const float* __restrict__ alphas,     // (N_ALPHA,)
    const float* __restrict__ log_alphas, // (N_ALPHA,)
    float2* __restrict__ xd)              // (NTIMES, NORB)
{
    __shared__ float2 tile[32][33];

    const float la0    = log_alphas[0];
    const float inv_la = 1.0f / (log_alphas[1] - la0);
    const float alo    = alphas[0];
    const float ahi    = alphas[N_ALPHA - 1];

    const int t0 = blockIdx.x * 32;
    const int o0 = blockIdx.y * 32;
    const int tx = threadIdx.x, ty = threadIdx.y;

    #pragma unroll
    for (int r = 0; r < 4; ++r) {
        int orb = o0 + ty + 8 * r;
        int t   = t0 + tx;
        float2 v = make_float2(0.0f, __builtin_inff());
        if (orb < NORB && t < NTIMES) {
            float a  = alpha[(size_t)orb * NTIMES + t];
            float dm = dMag [(size_t)orb * NTIMES + t];
            bool geom = (a >= alo) && (a <= ahi);
            float x = (log10f(a) - la0) * inv_la;
            float xc = fminf(fmaxf(x, 0.0f), 198.9999f);
            v = make_float2(xc, geom ? dm : __builtin_inff());
        }
        tile[ty + 8 * r][tx] = v;
    }
    __syncthreads();
    #pragma unroll
    for (int r = 0; r < 4; ++r) {
        int tt  = ty + 8 * r;
        int t   = t0 + tt;
        int orb = o0 + tx;
        if (orb < NORB && t < NTIMES)
            xd[(size_t)t * NORB + orb] = tile[tx][tt];
    }
}

// ---------------------------------------------------------------------------
// Pass 2: block = one t, 1024 threads (16 waves, 2 blocks/CU = 32 waves/CU).
// Lane = s*32+k.  Slab staged as (g0, slope) float2, row stride 201 pairs:
// gather = one ds_read_b64, banks (18k+2a)%32 -> <=2-way (free).
// Main loop guard-free (62 iters) + 1 tail iter for waves 0..7.
// Per eval: cvt, fract, lshl_add, fma, cmp+acc = 5 VALU + 1 ds_read_b64.
// ---------------------------------------------------------------------------
__global__ __launch_bounds__(BLOCK) void pdet5_kernel(
    const float2* __restrict__ xd,        // (NTIMES, NORB)
    const float* __restrict__ fZ_vals,    // (NTIMES,)
    const float* __restrict__ kEZ_val,    // scalar
    const float* __restrict__ grid,       // (N_FZ, N_KEZ, N_TINT, N_ALPHA)
    const float* __restrict__ kEZs,       // (N_KEZ,)
    const float* __restrict__ log_fZs,    // (N_FZ,)
    float* __restrict__ out)              // (NTIMES, N_TINT)
{
    __shared__ float2 gs[N_TINT * P_LD];  // 48240 B: (g0, g1-g0)
    __shared__ int    wsum[16][N_TINT];

    const int t   = blockIdx.x;
    const int tid = threadIdx.x;

    // fZ0 (double to match np at floor boundaries)
    const float lf0    = log_fZs[0];
    const float lfstep = log_fZs[1] - lf0;
    double fZ_ind = (log10((double)fZ_vals[t]) - (double)lf0) * (1.0 / (double)lfstep);
    int fZ0 = (int)floor(fZ_ind) + 1;
    fZ0 = min(max(fZ0, 0), N_FZ - 2);

    // searchsorted(kEZs, kEZ_val, 'right') - 1
    const float kv = kEZ_val[0];
    int kidx = -1;
    #pragma unroll
    for (int i = 0; i < N_KEZ; ++i) kidx += (kEZs[i] <= kv) ? 1 : 0;
    if (kidx < 0) kidx += N_KEZ;

    // ---- stage slab as (g0, slope) pairs; div-free task decode ----
    // tasks m = k*64 + c, k<30, c<50: float4 chunk at row k, cols 4c..4c+3.
    const float* src = grid + ((size_t)fZ0 * N_KEZ + kidx) * (N_TINT * N_ALPHA);
    for (int m = tid; m < N_TINT * 64; m += BLOCK) {
        int k = m >> 6;
        int c = m & 63;
        if (c < 50) {
            const float* p = src + (size_t)k * N_ALPHA + 4 * c;
            float4 v = *(const float4*)p;
            float nxt = p[4];                  // in-bounds within grid
            int b = k * P_LD + 4 * c;
            gs[b + 0] = make_float2(v.x, v.y - v.x);
            gs[b + 1] = make_float2(v.y, v.z - v.y);
            gs[b + 2] = make_float2(v.z, v.w - v.z);
            gs[b + 3] = make_float2(v.w, nxt - v.w);
        }
    }
    __syncthreads();

    const int lane = tid & 63;
    const int w    = tid >> 6;                  // wave 0..15
    const int s    = lane >> 5;                 // orbit slot within wave
    const int k    = lane & 31;                 // tint (30 used)
    const int krow = min(k, N_TINT - 1) * P_LD; // idle lanes alias row 29

    // lane's orbit stream: pairs p = w + 16*i, orbit = 2p+s
    const float2* xp = xd + (size_t)t * NORB + 2 * w + s;

    int cnt = 0;
    #pragma unroll 9
    for (int i = 0; i < 62; ++i) {              // p <= 15+16*61 = 991 < 1000
        float2 v = xp[32 * i];                  // broadcast (2 addrs/wave)
        unsigned a0 = (unsigned)v.x;            // v_cvt_u32_f32 (trunc)
        float dal = __builtin_amdgcn_fractf(v.x);
        float2 p = gs[krow + a0];               // one ds_read_b64
        float dim = fmaf(dal, p.y, p.x);
        cnt += (v.y < dim) ? 1 : 0;
    }
    if (w < 8) {                                // tail: p = 992+w < 1000
        float2 v = xp[32 * 62];
        unsigned a0 = (unsigned)v.x;
        float dal = __builtin_amdgcn_fractf(v.x);
        float2 p = gs[krow + a0];
        float dim = fmaf(dal, p.y, p.x);
        cnt += (v.y < dim) ? 1 : 0;
    }

    // combine orbit slots, then cross-wave
    cnt += __shfl_xor(cnt, 32, 64);
    if (s == 0 && k < N_TINT) wsum[w][k] = cnt;
    __syncthreads();

    if (tid < N_TINT) {
        int tot = 0;
        #pragma unroll
        for (int w2 = 0; w2 < 16; ++w2) tot += wsum[w2][tid];
        out[(size_t)t * N_TINT + tid] = (float)tot * (1.0f / NORB);
    }
}

// ---------------------------------------------------------------------------
// Fallback (no workspace): round-1 kernel, correct but slower.
// ---------------------------------------------------------------------------
__global__ __launch_bounds__(256) void pdet_kernel(
    const float* __restrict__ alpha, const float* __restrict__ dMag,
    const float* __restrict__ fZ_vals, const float* __restrict__ kEZ_val,
    const float* __restrict__ grid, const float* __restrict__ kEZs,
    const float* __restrict__ alphas, const float* __restrict__ log_fZs,
    const float* __restrict__ log_alphas, float* __restrict__ out)
{
    __shared__ float2 pairs[N_TINT * N_ALPHA];
    __shared__ int    wsum[4][N_TINT];

    const int t   = blockIdx.x;
    const int tid = threadIdx.x;

    const float la0    = log_alphas[0];
    const float inv_la = 1.0f / (log_alphas[1] - la0);
    const float alo    = alphas[0];
    const float ahi    = alphas[N_ALPHA - 1];

    const float lf0    = log_fZs[0];
    const float lfstep = log_fZs[1] - lf0;
    double fZ_ind = (log10((double)fZ_vals[t]) - (double)lf0) * (1.0 / (double)lfstep);
    int fZ0 = (int)floor(fZ_ind) + 1;
    fZ0 = min(max(fZ0, 0), N_FZ - 2);

    const float kv = kEZ_val[0];
    int kidx = -1;
    #pragma unroll
    for (int i = 0; i < N_KEZ; ++i) kidx += (kEZs[i] <= kv) ? 1 : 0;
    if (kidx < 0) kidx += N_KEZ;

    const float* src = grid + ((size_t)fZ0 * N_KEZ + kidx) * (N_TINT * N_ALPHA);
    const float4* src4 = (const float4*)src;
    for (int j = tid; j < (N_TINT * N_ALPHA) / 4; j += 256) {
        float4 v  = src4[j];
        float nxt = src[4 * j + 4];
        pairs[4 * j + 0] = make_float2(v.x, v.y);
        pairs[4 * j + 1] = make_float2(v.y, v.z);
        pairs[4 * j + 2] = make_float2(v.z, v.w);
        pairs[4 * j + 3] = make_float2(v.w, nxt);
    }
    __syncthreads();

    int cnt[N_TINT];
    #pragma unroll
    for (int k = 0; k < N_TINT; ++k) cnt[k] = 0;

    for (int orb = tid; orb < NORB; orb += 256) {
        float a  = alpha[(size_t)orb * NTIMES + t];
        float dm = dMag [(size_t)orb * NTIMES + t];
        bool geom = (a >= alo) && (a <= ahi);
        float a_ind = (log10f(a) - la0) * inv_la;
        int a0 = (int)a_ind;
        a0 = min(max(a0, 0), N_ALPHA - 1);
        float dal = a_ind - (float)a0;
        int a0s = min(a0, N_ALPHA - 2);
        if (!geom) dm = __builtin_inff();

        #pragma unroll
        for (int k = 0; k < N_TINT; ++k) {
            float2 p = pairs[k * N_ALPHA + a0s];
            float dim = p.x + dal * (p.y - p.x);
            cnt[k] += (dm < dim) ? 1 : 0;
        }
    }

    const int lane = tid & 63;
    const int wid  = tid >> 6;
    #pragma unroll
    for (int k = 0; k < N_TINT; ++k) {
        int c = cnt[k];
        c += __shfl_xor(c, 32, 64);
        c += __shfl_xor(c, 16, 64);
        c += __shfl_xor(c,  8, 64);
        c += __shfl_xor(c,  4, 64);
        c += __shfl_xor(c,  2, 64);
        c += __shfl_xor(c,  1, 64);
        if (lane == 0) wsum[wid][k] = c;
    }
    __syncthreads();

    if (tid < N_TINT) {
        int tot = wsum[0][tid] + wsum[1][tid] + wsum[2][tid] + wsum[3][tid];
        out[(size_t)t * N_TINT + tid] = (float)tot / (float)NORB;
    }
}

extern "C" void kernel_launch(void* const* d_in, const int* in_sizes, int n_in,
                              void* d_out, int out_size, void* d_ws, size_t ws_size,
                              hipStream_t stream) {
    const float* alpha      = (const float*)d_in[0];
    const float* dMag       = (const float*)d_in[1];
    const float* fZ_vals    = (const float*)d_in[2];
    const float* kEZ_val    = (const float*)d_in[3];
    const float* grid       = (const float*)d_in[4];
    const float* kEZs       = (const float*)d_in[5];
    const float* alphas     = (const float*)d_in[6];
    const float* log_fZs    = (const float*)d_in[7];
    const float* log_alphas = (const float*)d_in[8];
    float* out = (float*)d_out;

    const size_t need = (size_t)NTIMES * NORB * sizeof(float2);
    if (ws_size >= need) {
        dim3 gb((NTIMES + 31) / 32, (NORB + 31) / 32);
        dim3 tb(32, 8);
        prep_kernel<<<gb, tb, 0, stream>>>(alpha, dMag, alphas, log_alphas,
                                           (float2*)d_ws);
        pdet5_kernel<<<NTIMES, BLOCK, 0, stream>>>(
            (const float2*)d_ws, fZ_vals, kEZ_val, grid, kEZs, log_fZs, out);
    } else {
        pdet_kernel<<<NTIMES, 256, 0, stream>>>(
            alpha, dMag, fZ_vals, kEZ_val, grid, kEZs, alphas, log_fZs,
            log_alphas, out);
    }
}

// Round 6
// 119.900 us; speedup vs baseline: 1.1661x; 1.0752x over previous
//
#include <hip/hip_runtime.h>
#include <math.h>

#define N_FZ    60
#define N_KEZ   20
#define N_TINT  30
#define N_ALPHA 200
#define NORB    2000
#define NTIMES  1000
#define BLOCK   1024
#define PAIR_LD 34        // float2 per slab row: 272 B = 17 x 16 B (b128-aligned, odd block stride)
#define N_ROWS  199       // a0 ranges 0..198

// ---------------------------------------------------------------------------
// Pass 1: fused transpose + index precompute.
// xd[t][orb] = (xc, dm): xc = clamp(a_ind,0,198.9999) (a0=trunc, dal=fract);
// dm = +inf when geom-masked.
// ---------------------------------------------------------------------------
__global__ __launch_bounds__(256) void prep_kernel(
    const float* __restrict__ alpha,      // (NORB, NTIMES)
    const float* __restrict__ dMag,       // (NORB, NTIMES)
    const float* __restrict__ alphas,     // (N_ALPHA,)
    const float* __restrict__ log_alphas, // (N_ALPHA,)
    float2* __restrict__ xd)              // (NTIMES, NORB)
{
    __shared__ float2 tile[32][33];

    const float la0    = log_alphas[0];
    const float inv_la = 1.0f / (log_alphas[1] - la0);
    const float alo    = alphas[0];
    const float ahi    = alphas[N_ALPHA - 1];

    const int t0 = blockIdx.x * 32;
    const int o0 = blockIdx.y * 32;
    const int tx = threadIdx.x, ty = threadIdx.y;

    #pragma unroll
    for (int r = 0; r < 4; ++r) {
        int orb = o0 + ty + 8 * r;
        int t   = t0 + tx;
        float2 v = make_float2(0.0f, __builtin_inff());
        if (orb < NORB && t < NTIMES) {
            float a  = alpha[(size_t)orb * NTIMES + t];
            float dm = dMag [(size_t)orb * NTIMES + t];
            bool geom = (a >= alo) && (a <= ahi);
            float x = (log10f(a) - la0) * inv_la;
            float xc = fminf(fmaxf(x, 0.0f), 198.9999f);
            v = make_float2(xc, geom ? dm : __builtin_inff());
        }
        tile[ty + 8 * r][tx] = v;
    }
    __syncthreads();
    #pragma unroll
    for (int r = 0; r < 4; ++r) {
        int tt  = ty + 8 * r;
        int t   = t0 + tt;
        int orb = o0 + tx;
        if (orb < NORB && t < NTIMES)
            xd[(size_t)t * NORB + orb] = tile[tx][tt];
    }
}

// ---------------------------------------------------------------------------
// Pass 2: block = one t, 1024 threads (16 waves, 2 blocks/CU = 32 waves/CU).
// Slab TRANSPOSED in LDS: gsT[a][k] = (g0, slope), row stride 34 float2.
// Lane = s*16+h: s = orbit slot (4 orbits/wave-iter), h = tint-pair.
// One ds_read_b128 serves 2 tints of one orbit -> LDS instr count halved
// vs the b64 layout; VMEM/loop overhead also halved (31 iters).
// ---------------------------------------------------------------------------
__global__ __launch_bounds__(BLOCK) void pdet6_kernel(
    const float2* __restrict__ xd,        // (NTIMES, NORB)
    const float* __restrict__ fZ_vals,    // (NTIMES,)
    const float* __restrict__ kEZ_val,    // scalar
    const float* __restrict__ grid,       // (N_FZ, N_KEZ, N_TINT, N_ALPHA)
    const float* __restrict__ kEZs,       // (N_KEZ,)
    const float* __restrict__ log_fZs,    // (N_FZ,)
    float* __restrict__ out)              // (NTIMES, N_TINT)
{
    __shared__ __align__(16) float2 gsT[N_ROWS * PAIR_LD];  // 54128 B
    __shared__ int wsum[16][N_TINT];

    const int t   = blockIdx.x;
    const int tid = threadIdx.x;

    // fZ0 (double to match np at floor boundaries)
    const float lf0    = log_fZs[0];
    const float lfstep = log_fZs[1] - lf0;
    double fZ_ind = (log10((double)fZ_vals[t]) - (double)lf0) * (1.0 / (double)lfstep);
    int fZ0 = (int)floor(fZ_ind) + 1;
    fZ0 = min(max(fZ0, 0), N_FZ - 2);

    // searchsorted(kEZs, kEZ_val, 'right') - 1
    const float kv = kEZ_val[0];
    int kidx = -1;
    #pragma unroll
    for (int i = 0; i < N_KEZ; ++i) kidx += (kEZs[i] <= kv) ? 1 : 0;
    if (kidx < 0) kidx += N_KEZ;

    // ---- stage transposed slab: gsT[a][k] = (g[k][a], g[k][a+1]-g[k][a]) ----
    // div-free task decode: m = k*256 + a, k<30, a<199.  Reads coalesced in a.
    const float* src = grid + ((size_t)fZ0 * N_KEZ + kidx) * (N_TINT * N_ALPHA);
    for (int m = tid; m < N_TINT * 256; m += BLOCK) {
        int k = m >> 8;
        int a = m & 255;
        if (a < N_ROWS) {
            const float* p = src + (size_t)k * N_ALPHA + a;
            float g0 = p[0];
            float g1 = p[1];
            gsT[a * PAIR_LD + k] = make_float2(g0, g1 - g0);
        }
    }
    __syncthreads();

    const int lane = tid & 63;
    const int w    = tid >> 6;                  // wave 0..15
    const int s    = lane >> 4;                 // orbit slot 0..3
    const int h    = lane & 15;                 // tint pair 0..15
    const int hh   = (h < 15) ? h : 14;         // lane h=15 duplicates h=14 (discarded)

    const float2* row = xd + (size_t)t * NORB;

    int cnt_e = 0, cnt_o = 0;
    #pragma unroll 8
    for (int i = 0; i < 31; ++i) {              // q = w+16i <= 495 -> orbits < 1984
        int q = w + 16 * i;
        float2 v = row[4 * q + s];              // 4 addrs/wave -> broadcast-ish
        unsigned a0 = (unsigned)v.x;            // trunc (v_cvt_u32_f32)
        float dal = __builtin_amdgcn_fractf(v.x);
        float4 P = *reinterpret_cast<const float4*>(&gsT[a0 * PAIR_LD + 2 * hh]);
        cnt_e += (v.y < fmaf(dal, P.y, P.x)) ? 1 : 0;   // k = 2hh
        cnt_o += (v.y < fmaf(dal, P.w, P.z)) ? 1 : 0;   // k = 2hh+1
    }
    if (w < 4) {                                // tail: q = 496+w -> orbits 1984..1999
        int q = 496 + w;
        float2 v = row[4 * q + s];
        unsigned a0 = (unsigned)v.x;
        float dal = __builtin_amdgcn_fractf(v.x);
        float4 P = *reinterpret_cast<const float4*>(&gsT[a0 * PAIR_LD + 2 * hh]);
        cnt_e += (v.y < fmaf(dal, P.y, P.x)) ? 1 : 0;
        cnt_o += (v.y < fmaf(dal, P.w, P.z)) ? 1 : 0;
    }

    // sum over the 4 orbit slots (lanes l, l^16, l^32, l^48 share h)
    cnt_e += __shfl_xor(cnt_e, 16, 64);
    cnt_e += __shfl_xor(cnt_e, 32, 64);
    cnt_o += __shfl_xor(cnt_o, 16, 64);
    cnt_o += __shfl_xor(cnt_o, 32, 64);
    if (lane < 15) {                            // s==0, h<15
        wsum[w][2 * lane]     = cnt_e;
        wsum[w][2 * lane + 1] = cnt_o;
    }
    __syncthreads();

    if (tid < N_TINT) {
        int tot = 0;
        #pragma unroll
        for (int w2 = 0; w2 < 16; ++w2) tot += wsum[w2][tid];
        out[(size_t)t * N_TINT + tid] = (float)tot * (1.0f / NORB);
    }
}

// ---------------------------------------------------------------------------
// Fallback (no workspace): round-1 kernel, correct but slower.
// ---------------------------------------------------------------------------
__global__ __launch_bounds__(256) void pdet_kernel(
    const float* __restrict__ alpha, const float* __restrict__ dMag,
    const float* __restrict__ fZ_vals, const float* __restrict__ kEZ_val,
    const float* __restrict__ grid, const float* __restrict__ kEZs,
    const float* __restrict__ alphas, const float* __restrict__ log_fZs,
    const float* __restrict__ log_alphas, float* __restrict__ out)
{
    __shared__ float2 pairs[N_TINT * (N_ALPHA + 1)];
    __shared__ int    wsum[4][N_TINT];

    const int t   = blockIdx.x;
    const int tid = threadIdx.x;

    const float la0    = log_alphas[0];
    const float inv_la = 1.0f / (log_alphas[1] - la0);
    const float alo    = alphas[0];
    const float ahi    = alphas[N_ALPHA - 1];

    const float lf0    = log_fZs[0];
    const float lfstep = log_fZs[1] - lf0;
    double fZ_ind = (log10((double)fZ_vals[t]) - (double)lf0) * (1.0 / (double)lfstep);
    int fZ0 = (int)floor(fZ_ind) + 1;
    fZ0 = min(max(fZ0, 0), N_FZ - 2);

    const float kv = kEZ_val[0];
    int kidx = -1;
    #pragma unroll
    for (int i = 0; i < N_KEZ; ++i) kidx += (kEZs[i] <= kv) ? 1 : 0;
    if (kidx < 0) kidx += N_KEZ;

    const float* src = grid + ((size_t)fZ0 * N_KEZ + kidx) * (N_TINT * N_ALPHA);
    for (int j = tid; j < N_TINT * N_ALPHA; j += 256) {
        int k = j / N_ALPHA;
        int a = j - k * N_ALPHA;
        float g0 = src[j];
        float g1 = (a < N_ALPHA - 1) ? src[j + 1] : g0;
        pairs[k * (N_ALPHA + 1) + a] = make_float2(g0, g1);
    }
    __syncthreads();

    int cnt[N_TINT];
    #pragma unroll
    for (int k = 0; k < N_TINT; ++k) cnt[k] = 0;

    for (int orb = tid; orb < NORB; orb += 256) {
        float a  = alpha[(size_t)orb * NTIMES + t];
        float dm = dMag [(size_t)orb * NTIMES + t];
        bool geom = (a >= alo) && (a <= ahi);
        float a_ind = (log10f(a) - la0) * inv_la;
        int a0 = (int)a_ind;
        a0 = min(max(a0, 0), N_ALPHA - 1);
        float dal = a_ind - (float)a0;
        int a0s = min(a0, N_ALPHA - 2);
        if (!geom) dm = __builtin_inff();

        #pragma unroll
        for (int k = 0; k < N_TINT; ++k) {
            float2 p = pairs[k * (N_ALPHA + 1) + a0s];
            float dim = p.x + dal * (p.y - p.x);
            cnt[k] += (dm < dim) ? 1 : 0;
        }
    }

    const int lane = tid & 63;
    const int wid  = tid >> 6;
    #pragma unroll
    for (int k = 0; k < N_TINT; ++k) {
        int c = cnt[k];
        c += __shfl_xor(c, 32, 64);
        c += __shfl_xor(c, 16, 64);
        c += __shfl_xor(c,  8, 64);
        c += __shfl_xor(c,  4, 64);
        c += __shfl_xor(c,  2, 64);
        c += __shfl_xor(c,  1, 64);
        if (lane == 0) wsum[wid][k] = c;
    }
    __syncthreads();

    if (tid < N_TINT) {
        int tot = wsum[0][tid] + wsum[1][tid] + wsum[2][tid] + wsum[3][tid];
        out[(size_t)t * N_TINT + tid] = (float)tot / (float)NORB;
    }
}

extern "C" void kernel_launch(void* const* d_in, const int* in_sizes, int n_in,
                              void* d_out, int out_size, void* d_ws, size_t ws_size,
                              hipStream_t stream) {
    const float* alpha      = (const float*)d_in[0];
    const float* dMag       = (const float*)d_in[1];
    const float* fZ_vals    = (const float*)d_in[2];
    const float* kEZ_val    = (const float*)d_in[3];
    const float* grid       = (const float*)d_in[4];
    const float* kEZs       = (const float*)d_in[5];
    const float* alphas     = (const float*)d_in[6];
    const float* log_fZs    = (const float*)d_in[7];
    const float* log_alphas = (const float*)d_in[8];
    float* out = (float*)d_out;

    const size_t need = (size_t)NTIMES * NORB * sizeof(float2);
    if (ws_size >= need) {
        dim3 gb((NTIMES + 31) / 32, (NORB + 31) / 32);
        dim3 tb(32, 8);
        prep_kernel<<<gb, tb, 0, stream>>>(alpha, dMag, alphas, log_alphas,
                                           (float2*)d_ws);
        pdet6_kernel<<<NTIMES, BLOCK, 0, stream>>>(
            (const float2*)d_ws, fZ_vals, kEZ_val, grid, kEZs, log_fZs, out);
    } else {
        pdet_kernel<<<NTIMES, 256, 0, stream>>>(
            alpha, dMag, fZ_vals, kEZ_val, grid, kEZs, alphas, log_fZs,
            log_alphas, out);
    }
}

// Round 9
// 114.987 us; speedup vs baseline: 1.2159x; 1.0427x over previous
//
#include <hip/hip_runtime.h>
#include <math.h>

#define N_FZ    60
#define N_KEZ   20
#define N_TINT  30
#define N_ALPHA 200
#define NORB    2000
#define NTIMES  1000
#define BLOCK   1024
#define PAIR_LD 34        // float2 per slab row: 272 B = 17 x 16 B (b128-aligned, odd block stride)
#define N_ROWS  199       // a0 ranges 0..198

// ---------------------------------------------------------------------------
// Pass 1: fused transpose + index precompute.
// xd[t][orb] = (xc, dm): xc = clamp(a_ind,0,198.9999) (a0=trunc, dal=fract);
// dm = +inf when geom-masked.
// ---------------------------------------------------------------------------
__global__ __launch_bounds__(256) void prep_kernel(
    const float* __restrict__ alpha,      // (NORB, NTIMES)
    const float* __restrict__ dMag,       // (NORB, NTIMES)
    const float* __restrict__ alphas,     // (N_ALPHA,)
    const float* __restrict__ log_alphas, // (N_ALPHA,)
    float2* __restrict__ xd)              // (NTIMES, NORB)
{
    __shared__ float2 tile[32][33];

    const float la0    = log_alphas[0];
    const float inv_la = 1.0f / (log_alphas[1] - la0);
    const float alo    = alphas[0];
    const float ahi    = alphas[N_ALPHA - 1];

    const int t0 = blockIdx.x * 32;
    const int o0 = blockIdx.y * 32;
    const int tx = threadIdx.x, ty = threadIdx.y;

    #pragma unroll
    for (int r = 0; r < 4; ++r) {
        int orb = o0 + ty + 8 * r;
        int t   = t0 + tx;
        float2 v = make_float2(0.0f, __builtin_inff());
        if (orb < NORB && t < NTIMES) {
            float a  = alpha[(size_t)orb * NTIMES + t];
            float dm = dMag [(size_t)orb * NTIMES + t];
            bool geom = (a >= alo) && (a <= ahi);
            float x = (log10f(a) - la0) * inv_la;
            float xc = fminf(fmaxf(x, 0.0f), 198.9999f);
            v = make_float2(xc, geom ? dm : __builtin_inff());
        }
        tile[ty + 8 * r][tx] = v;
    }
    __syncthreads();
    #pragma unroll
    for (int r = 0; r < 4; ++r) {
        int tt  = ty + 8 * r;
        int t   = t0 + tt;
        int orb = o0 + tx;
        if (orb < NORB && t < NTIMES)
            xd[(size_t)t * NORB + orb] = tile[tx][tt];
    }
}

// ---------------------------------------------------------------------------
// Pass 2: block = one t, 1024 threads (16 waves, 2 blocks/CU = 32 waves/CU).
// Slab TRANSPOSED in LDS: gsT[a][k] = (g0, slope), row stride 34 float2.
// Lane = s*16+h: s = orbit-slot (4), h = tint-pair (16, 15 used).
// Per lane-iter: one float4 VMEM = 2 orbit records; per record one
// ds_read_b128 serves 2 tints.  Stream: i = w + 16j, records at float4
// index 4i+s = (4w+s) + 64j  ->  rp[64*j]  (R8 bug was rp[16*j]).
// ---------------------------------------------------------------------------
__global__ __launch_bounds__(BLOCK) void pdet7_kernel(
    const float2* __restrict__ xd,        // (NTIMES, NORB)
    const float* __restrict__ fZ_vals,    // (NTIMES,)
    const float* __restrict__ kEZ_val,    // scalar
    const float* __restrict__ grid,       // (N_FZ, N_KEZ, N_TINT, N_ALPHA)
    const float* __restrict__ kEZs,       // (N_KEZ,)
    const float* __restrict__ log_fZs,    // (N_FZ,)
    float* __restrict__ out)              // (NTIMES, N_TINT)
{
    __shared__ __align__(16) float2 gsT[N_ROWS * PAIR_LD];  // 54128 B
    __shared__ int wsum[16][N_TINT];

    const int t   = blockIdx.x;
    const int tid = threadIdx.x;

    // fZ0 (double to match np at floor boundaries)
    const float lf0    = log_fZs[0];
    const float lfstep = log_fZs[1] - lf0;
    double fZ_ind = (log10((double)fZ_vals[t]) - (double)lf0) * (1.0 / (double)lfstep);
    int fZ0 = (int)floor(fZ_ind) + 1;
    fZ0 = min(max(fZ0, 0), N_FZ - 2);

    // searchsorted(kEZs, kEZ_val, 'right') - 1
    const float kv = kEZ_val[0];
    int kidx = -1;
    #pragma unroll
    for (int i = 0; i < N_KEZ; ++i) kidx += (kEZs[i] <= kv) ? 1 : 0;
    if (kidx < 0) kidx += N_KEZ;

    // ---- stage transposed slab: gsT[a][k] = (g[k][a], g[k][a+1]-g[k][a]) ----
    const float* src = grid + ((size_t)fZ0 * N_KEZ + kidx) * (N_TINT * N_ALPHA);
    for (int m = tid; m < N_TINT * 256; m += BLOCK) {
        int k = m >> 8;
        int a = m & 255;
        if (a < N_ROWS) {
            const float* p = src + (size_t)k * N_ALPHA + a;
            float g0 = p[0];
            float g1 = p[1];
            gsT[a * PAIR_LD + k] = make_float2(g0, g1 - g0);
        }
    }
    __syncthreads();

    const int lane = tid & 63;
    const int w    = tid >> 6;                  // wave 0..15
    const int s    = lane >> 4;                 // orbit slot 0..3
    const int h    = lane & 15;                 // tint pair 0..15
    const int hh   = (h < 15) ? h : 14;         // lane h=15 duplicates h=14 (discarded)
    const int hoff = 2 * hh;                    // pair offset within row

    const float2* row = xd + (size_t)t * NORB;

    int cnt_e = 0, cnt_o = 0;

    // lane's record pair for stream index i = w+16j lives at float4 index
    // 4i+s = (4w+s) + 64j; rp base is float4 index 4w+s (16B aligned).
    const float4* rp = reinterpret_cast<const float4*>(row + 8 * w + 2 * s);

    #pragma unroll 5
    for (int j = 0; j < 15; ++j) {              // i = w+16j <= 239 < 250
        float4 v = rp[64 * j];                  // 2 records (orbits 8i+2s, +1)
        // record A
        unsigned aA = (unsigned)v.x;
        float dalA = __builtin_amdgcn_fractf(v.x);
        // record B
        unsigned aB = (unsigned)v.z;
        float dalB = __builtin_amdgcn_fractf(v.z);
        float4 PA = *reinterpret_cast<const float4*>(&gsT[aA * PAIR_LD + hoff]);
        float4 PB = *reinterpret_cast<const float4*>(&gsT[aB * PAIR_LD + hoff]);
        cnt_e += (v.y < fmaf(dalA, PA.y, PA.x)) ? 1 : 0;
        cnt_o += (v.y < fmaf(dalA, PA.w, PA.z)) ? 1 : 0;
        cnt_e += (v.w < fmaf(dalB, PB.y, PB.x)) ? 1 : 0;
        cnt_o += (v.w < fmaf(dalB, PB.w, PB.z)) ? 1 : 0;
    }
    if (w < 10) {                               // tail: i = 240+w <= 249
        float4 v = rp[64 * 15];
        unsigned aA = (unsigned)v.x;
        float dalA = __builtin_amdgcn_fractf(v.x);
        unsigned aB = (unsigned)v.z;
        float dalB = __builtin_amdgcn_fractf(v.z);
        float4 PA = *reinterpret_cast<const float4*>(&gsT[aA * PAIR_LD + hoff]);
        float4 PB = *reinterpret_cast<const float4*>(&gsT[aB * PAIR_LD + hoff]);
        cnt_e += (v.y < fmaf(dalA, PA.y, PA.x)) ? 1 : 0;
        cnt_o += (v.y < fmaf(dalA, PA.w, PA.z)) ? 1 : 0;
        cnt_e += (v.w < fmaf(dalB, PB.y, PB.x)) ? 1 : 0;
        cnt_o += (v.w < fmaf(dalB, PB.w, PB.z)) ? 1 : 0;
    }

    // sum over the 4 orbit slots (lanes l, l^16, l^32, l^48 share h)
    cnt_e += __shfl_xor(cnt_e, 16, 64);
    cnt_e += __shfl_xor(cnt_e, 32, 64);
    cnt_o += __shfl_xor(cnt_o, 16, 64);
    cnt_o += __shfl_xor(cnt_o, 32, 64);
    if (lane < 15) {                            // s==0, h<15
        wsum[w][2 * lane]     = cnt_e;
        wsum[w][2 * lane + 1] = cnt_o;
    }
    __syncthreads();

    if (tid < N_TINT) {
        int tot = 0;
        #pragma unroll
        for (int w2 = 0; w2 < 16; ++w2) tot += wsum[w2][tid];
        out[(size_t)t * N_TINT + tid] = (float)tot * (1.0f / NORB);
    }
}

// ---------------------------------------------------------------------------
// Fallback (no workspace): correct but slower.
// ---------------------------------------------------------------------------
__global__ __launch_bounds__(256) void pdet_kernel(
    const float* __restrict__ alpha, const float* __restrict__ dMag,
    const float* __restrict__ fZ_vals, const float* __restrict__ kEZ_val,
    const float* __restrict__ grid, const float* __restrict__ kEZs,
    const float* __restrict__ alphas, const float* __restrict__ log_fZs,
    const float* __restrict__ log_alphas, float* __restrict__ out)
{
    __shared__ float2 pairs[N_TINT * (N_ALPHA + 1)];
    __shared__ int    wsum[4][N_TINT];

    const int t   = blockIdx.x;
    const int tid = threadIdx.x;

    const float la0    = log_alphas[0];
    const float inv_la = 1.0f / (log_alphas[1] - la0);
    const float alo    = alphas[0];
    const float ahi    = alphas[N_ALPHA - 1];

    const float lf0    = log_fZs[0];
    const float lfstep = log_fZs[1] - lf0;
    double fZ_ind = (log10((double)fZ_vals[t]) - (double)lf0) * (1.0 / (double)lfstep);
    int fZ0 = (int)floor(fZ_ind) + 1;
    fZ0 = min(max(fZ0, 0), N_FZ - 2);

    const float kv = kEZ_val[0];
    int kidx = -1;
    #pragma unroll
    for (int i = 0; i < N_KEZ; ++i) kidx += (kEZs[i] <= kv) ? 1 : 0;
    if (kidx < 0) kidx += N_KEZ;

    const float* src = grid + ((size_t)fZ0 * N_KEZ + kidx) * (N_TINT * N_ALPHA);
    for (int j = tid; j < N_TINT * N_ALPHA; j += 256) {
        int k = j / N_ALPHA;
        int a = j - k * N_ALPHA;
        float g0 = src[j];
        float g1 = (a < N_ALPHA - 1) ? src[j + 1] : g0;
        pairs[k * (N_ALPHA + 1) + a] = make_float2(g0, g1);
    }
    __syncthreads();

    int cnt[N_TINT];
    #pragma unroll
    for (int k = 0; k < N_TINT; ++k) cnt[k] = 0;

    for (int orb = tid; orb < NORB; orb += 256) {
        float a  = alpha[(size_t)orb * NTIMES + t];
        float dm = dMag [(size_t)orb * NTIMES + t];
        bool geom = (a >= alo) && (a <= ahi);
        float a_ind = (log10f(a) - la0) * inv_la;
        int a0 = (int)a_ind;
        a0 = min(max(a0, 0), N_ALPHA - 1);
        float dal = a_ind - (float)a0;
        int a0s = min(a0, N_ALPHA - 2);
        if (!geom) dm = __builtin_inff();

        #pragma unroll
        for (int k = 0; k < N_TINT; ++k) {
            float2 p = pairs[k * (N_ALPHA + 1) + a0s];
            float dim = p.x + dal * (p.y - p.x);
            cnt[k] += (dm < dim) ? 1 : 0;
        }
    }

    const int lane = tid & 63;
    const int wid  = tid >> 6;
    #pragma unroll
    for (int k = 0; k < N_TINT; ++k) {
        int c = cnt[k];
        c += __shfl_xor(c, 32, 64);
        c += __shfl_xor(c, 16, 64);
        c += __shfl_xor(c,  8, 64);
        c += __shfl_xor(c,  4, 64);
        c += __shfl_xor(c,  2, 64);
        c += __shfl_xor(c,  1, 64);
        if (lane == 0) wsum[wid][k] = c;
    }
    __syncthreads();

    if (tid < N_TINT) {
        int tot = wsum[0][tid] + wsum[1][tid] + wsum[2][tid] + wsum[3][tid];
        out[(size_t)t * N_TINT + tid] = (float)tot / (float)NORB;
    }
}

extern "C" void kernel_launch(void* const* d_in, const int* in_sizes, int n_in,
                              void* d_out, int out_size, void* d_ws, size_t ws_size,
                              hipStream_t stream) {
    const float* alpha      = (const float*)d_in[0];
    const float* dMag       = (const float*)d_in[1];
    const float* fZ_vals    = (const float*)d_in[2];
    const float* kEZ_val    = (const float*)d_in[3];
    const float* grid       = (const float*)d_in[4];
    const float* kEZs       = (const float*)d_in[5];
    const float* alphas     = (const float*)d_in[6];
    const float* log_fZs    = (const float*)d_in[7];
    const float* log_alphas = (const float*)d_in[8];
    float* out = (float*)d_out;

    const size_t need = (size_t)NTIMES * NORB * sizeof(float2);
    if (ws_size >= need) {
        dim3 gb((NTIMES + 31) / 32, (NORB + 31) / 32);
        dim3 tb(32, 8);
        prep_kernel<<<gb, tb, 0, stream>>>(alpha, dMag, alphas, log_alphas,
                                           (float2*)d_ws);
        pdet7_kernel<<<NTIMES, BLOCK, 0, stream>>>(
            (const float2*)d_ws, fZ_vals, kEZ_val, grid, kEZs, log_fZs, out);
    } else {
        pdet_kernel<<<NTIMES, 256, 0, stream>>>(
            alpha, dMag, fZ_vals, kEZ_val, grid, kEZs, alphas, log_fZs,
            log_alphas, out);
    }
}